// Round 9
// baseline (293.542 us; speedup 1.0000x reference)
//
#include <hip/hip_runtime.h>
#include <hip/hip_bf16.h>

#define E_CNT 160000
#define N_CNT 10000

#define INV_STEP   2.125f          /* 17/8 */
#define EMB_C      33.734292f      /* 1.14136 * e^2 * sqrt(16) */
#define INVS320    0.05590170f     /* 1/sqrt(320) */
#define INVS8      0.35355339f     /* 1/sqrt(8)   */
#define INV_SQRT3  0.57735027f
#define KSCALE     0.051031036f    /* 0.25 (w/sqrt16) * 1/sqrt(24) (fctp norm) */

/* ---- workspace layout (float-sized offsets) ---- */
#define OFF_FLAG   0          /* 16 floats reserved (int flag at [0]) */
#define OFF_EAF    400016     /* 640000 */
#define OFF_AMFF   1040016    /* 160000 */
#define OFF_WK1F   1200656    /* 256 */
#define OFF_WV1F   1200912    /* 256 */
#define OFF_P      1219600    /* 400000 */
#define OFF_EXPV   1619600    /* 160000 (dst-sorted order, fp32) */
#define OFF_VBUF   1779600    /* E*40 bf16 = 12.8 MB (dst-sorted order) */
#define OFF_DEG    8179600    /* 10000 ints (dst); reused as Z (zeroed at end of scan) */
#define OFF_Z      8179600    /* alias of OFF_DEG */
#define OFF_DEG2   8189600    /* 10000 ints (src) -- adjacent to DEG: single zero range */
#define OFF_START  8199600    /* 10001 ints */
#define OFF_START2 8209601    /* 10001 ints */
#define OFF_CURS   8219602    /* 10000 ints */
#define OFF_CURS2  8229602    /* 10000 ints */
#define OFF_DPOS   8239602    /* 160000 ints: dst-position of edge at src-sorted slot */
#define OFF_ELIST2 8399602    /* 160000 ints */
#define OFF_G      8559632    /* G rows: 16*10000*96 u32 = 61.44 MB (same extent as before) */
/* total 23,919,632 floats = 95.7 MB (same extent as R5-R23 -- verified mapped) */

/* R24 G layout: channel-PAIR interleaved rows. u32 at
   ((p*8 + jj)*10000 + n)*96 + k  holds (bf16 G_{c=2jj}[k], bf16 G_{c=2jj+1}[k]).
   Row per (pass, jj, src) = 96 u32 = 384B contiguous; k semantics = old out[] index:
   0..15 G1(o0,hs) | 16..23 G2(t2a,hc) | 24..47 G3(o1,hs) | 48..95 G4 (s1-dot, /sqrt3 baked). */

static __device__ __forceinline__ float bf2f(__hip_bfloat16 b) { return __bfloat162float(b); }
static __device__ __forceinline__ float sanitize(float v) {
    return fminf(fmaxf(v, -1e30f), 1e30f);
}
static __device__ __forceinline__ unsigned short f2bf(float f) {
    unsigned x = __float_as_uint(f);
    unsigned r = (x + 0x7fffu + ((x >> 16) & 1u)) >> 16;   /* RN-even */
    return (unsigned short)r;
}
static __device__ __forceinline__ float bflo(unsigned u) { return __uint_as_float(u << 16); }
static __device__ __forceinline__ float bfhi(unsigned u) { return __uint_as_float(u & 0xffff0000u); }
static __device__ __forceinline__ float2 bfp(unsigned u) {
    float2 r; r.x = bflo(u); r.y = bfhi(u); return r;
}

/* v_dot2_f32_bf16: d = a.lo*b.lo + a.hi*b.hi + c  (2 bf16 MACs, no unpack) */
static __device__ __forceinline__ float dot2bf(unsigned a, unsigned b, float c)
{
    float d;
    asm("v_dot2_f32_bf16 %0, %1, %2, %3" : "=v"(d) : "v"(a), "v"(b), "v"(c));
    return d;
}
/* v_cvt_pk_bf16_f32: pack two f32 -> u32 of 2 bf16 (RN) [guide m240: gfx950-verified] */
static __device__ __forceinline__ unsigned cvtpk2(float lo, float hi)
{
    unsigned r;
    asm("v_cvt_pk_bf16_f32 %0, %1, %2" : "=v"(r) : "v"(lo), "v"(hi));
    return r;
}
/* Dekker split of coefficient pair: ph = bf16(a), pl = bf16(a - bf16(a)).
   Applying ph then pl via dot2 keeps coefficient accurate to ~16 bits ->
   numerics >= the old f32-coefficient path (G's own bf16 noise dominates). */
static __device__ __forceinline__ void splitpk(float a0, float a1, unsigned& ph, unsigned& pl)
{
    ph = cvtpk2(a0, a1);
    pl = cvtpk2(a0 - bflo(ph), a1 - bfhi(ph));
}

/* load 4 consecutive floats from a maybe-bf16 / maybe-f32 buffer at element quad index i4 */
static __device__ __forceinline__ float4 load4(const void* p, int i4, int f32)
{
    if (f32) return ((const float4*)p)[i4];
    uint2 u = ((const uint2*)p)[i4];
    float4 r;
    r.x = bflo(u.x); r.y = bfhi(u.x);
    r.z = bflo(u.y); r.w = bfhi(u.y);
    return r;
}

/* 8-wide vector load: bf16 = one uint4 (16 B), f32 = two float4. p must be 16B-aligned. */
static __device__ __forceinline__ void ld8(const float* p, float (&r)[8])
{
    float4 a = ((const float4*)p)[0];
    float4 b = ((const float4*)p)[1];
    r[0] = a.x; r[1] = a.y; r[2] = a.z; r[3] = a.w;
    r[4] = b.x; r[5] = b.y; r[6] = b.z; r[7] = b.w;
}
static __device__ __forceinline__ void ld8(const __hip_bfloat16* p, float (&r)[8])
{
    uint4 u = *(const uint4*)p;
    r[0] = bflo(u.x); r[1] = bfhi(u.x); r[2] = bflo(u.y); r[3] = bfhi(u.y);
    r[4] = bflo(u.z); r[5] = bfhi(u.z); r[6] = bflo(u.w); r[7] = bfhi(u.w);
}

// ---------------- init: zero DEG/DEG2 (20000 ints) + detect flag (block 0, wave 0) ----------------
__global__ __launch_bounds__(256) void init_kernel(
    const unsigned short* __restrict__ xb, float* __restrict__ ws)
{
    const int idx = blockIdx.x * 256 + threadIdx.x;    /* 79 blocks -> 20224 threads */
    if (idx < 20000) ((int*)(ws + OFF_DEG))[idx] = 0;
    if (blockIdx.x == 0 && threadIdx.x < 64) {
        const int lane = threadIdx.x;
        unsigned e0 = (unsigned)((xb[2 * lane] >> 7) & 0xFF);        /* even u16 = fp32 low halves */
        unsigned e1 = (unsigned)((xb[128 + 2 * lane] >> 7) & 0xFF);
        int c = (e0 >= 141 ? 1 : 0) + (e1 >= 141 ? 1 : 0);
#pragma unroll
        for (int off = 1; off < 64; off <<= 1) c += __shfl_xor(c, off);
        if (lane == 0) *(int*)ws = (c >= 8) ? 1 : 0;   /* 1 = inputs are fp32 */
    }
}

// ---------------- prep body: ingest EA/AMF/W1 + degree atomics ----------------
static __device__ __forceinline__ void do_prep(
    const void* __restrict__ ea, const void* __restrict__ amf,
    const void* __restrict__ Wk1, const void* __restrict__ Wv1,
    const int* __restrict__ ei, float* __restrict__ ws, int i, int f32)
{
    if (i < 160000) ((float4*)(ws + OFF_EAF))[i] = load4(ea, i, f32);
    if (i < 40000) {
        ((float4*)(ws + OFF_AMFF))[i] = load4(amf, i, f32);
#pragma unroll
        for (int k = 0; k < 4; ++k) {
            atomicAdd((int*)(ws + OFF_DEG)  + ei[E_CNT + 4 * i + k], 1);   /* dst degree */
            atomicAdd((int*)(ws + OFF_DEG2) + ei[4 * i + k], 1);           /* src degree */
        }
    }
    if (i < 64) {
        ((float4*)(ws + OFF_WK1F))[i] = load4(Wk1, i, f32);
        ((float4*)(ws + OFF_WV1F))[i] = load4(Wv1, i, f32);
    }
}

// ---------------- G builder: computes out[96] for (n,p,c), then pair-packed store ----------------
/* R24: lanes are remapped so lane L and L^1 hold channels (2jj, 2jj+1) of the same n.
   After compute, 96 shfl_xor(1) exchanges + pair-pack to the interleaved row layout.
   G VALUES are bit-identical to before (same f2bf); only the arrangement changed. */
template <typename T>
static __device__ __forceinline__ void build_G(
    const T* __restrict__ x, const T* __restrict__ W2b, int n, int p, int c, int u,
    float* __restrict__ ws)
{
    float xs[40];
#pragma unroll
    for (int q = 0; q < 5; ++q) ld8(x + n * 40 + q * 8, *(float(*)[8])(xs + q * 8));
    const T* W2 = W2b + c * 576;

    float out[96];
#pragma unroll
    for (int k = 0; k < 96; ++k) out[k] = 0.f;

    /* seg1 */
#pragma unroll
    for (int uu = 0; uu < 16; ++uu) {
        float r0[8], r1[8];
        ld8(W2 + uu * 16, r0);
        ld8(W2 + uu * 16 + 8, r1);
        const float xv = xs[uu];
#pragma unroll
        for (int w = 0; w < 8; ++w) {
            out[w]     = fmaf(r0[w], xv, out[w]);
            out[8 + w] = fmaf(r1[w], xv, out[8 + w]);
        }
    }
    /* seg2 */
#pragma unroll
    for (int uu = 0; uu < 16; ++uu) {
        float r[8];
        ld8(W2 + 256 + uu * 8, r);
        const float xv = xs[uu];
#pragma unroll
        for (int w = 0; w < 8; ++w) out[16 + w] = fmaf(r[w], xv, out[16 + w]);
    }
    /* seg3 */
#pragma unroll
    for (int uu = 0; uu < 8; ++uu) {
        float r[8];
        ld8(W2 + 384 + uu * 8, r);
        const float a0 = xs[16 + uu * 3 + 0];
        const float a1 = xs[16 + uu * 3 + 1];
        const float a2 = xs[16 + uu * 3 + 2];
#pragma unroll
        for (int w = 0; w < 8; ++w) {
            out[24 + w * 3 + 0] = fmaf(r[w], a0, out[24 + w * 3 + 0]);
            out[24 + w * 3 + 1] = fmaf(r[w], a1, out[24 + w * 3 + 1]);
            out[24 + w * 3 + 2] = fmaf(r[w], a2, out[24 + w * 3 + 2]);
        }
    }
    /* seg4 (scaled by 1/sqrt3 below) */
#pragma unroll
    for (int uu = 0; uu < 8; ++uu) {
        float r0[8], r1[8];
        ld8(W2 + 448 + uu * 16, r0);
        ld8(W2 + 448 + uu * 16 + 8, r1);
        const float a0 = xs[16 + uu * 3 + 0];
        const float a1 = xs[16 + uu * 3 + 1];
        const float a2 = xs[16 + uu * 3 + 2];
#pragma unroll
        for (int w = 0; w < 8; ++w) {
            out[48 + w * 3 + 0] = fmaf(r0[w], a0, out[48 + w * 3 + 0]);
            out[48 + w * 3 + 1] = fmaf(r0[w], a1, out[48 + w * 3 + 1]);
            out[48 + w * 3 + 2] = fmaf(r0[w], a2, out[48 + w * 3 + 2]);
            out[48 + (8 + w) * 3 + 0] = fmaf(r1[w], a0, out[48 + (8 + w) * 3 + 0]);
            out[48 + (8 + w) * 3 + 1] = fmaf(r1[w], a1, out[48 + (8 + w) * 3 + 1]);
            out[48 + (8 + w) * 3 + 2] = fmaf(r1[w], a2, out[48 + (8 + w) * 3 + 2]);
        }
    }
#pragma unroll
    for (int k = 0; k < 48; ++k) out[48 + k] *= INV_SQRT3;

    /* pair exchange + pack: even lane (u=0) stores k 0..47, odd lane k 48..95 */
    uint4 ov[12];
    unsigned* ou = (unsigned*)ov;
#pragma unroll
    for (int kk = 0; kk < 48; ++kk) {
        float oa = __shfl_xor(out[kk], 1);        /* even lane receives odd's out[kk]      */
        float ob = __shfl_xor(out[48 + kk], 1);   /* odd lane receives even's out[48+kk]   */
        float lov = u ? ob : out[kk];             /* c0 value at stored element            */
        float hiv = u ? out[48 + kk] : oa;        /* c1 value                              */
        ou[kk] = (unsigned)f2bf(lov) | ((unsigned)f2bf(hiv) << 16);
    }
    const int jj = (c >> 1) & 7;
    uint4* gb = (uint4*)(ws + OFF_G)
              + ((size_t)(p * 8 + jj) * 10000 + n) * 24 + u * 12;
#pragma unroll
    for (int q = 0; q < 12; ++q) gb[q] = ov[q];
}

// ---------------- P builder (vectorized loads) ----------------
template <typename T>
static __device__ __forceinline__ void build_P(
    const T* __restrict__ x, const T* __restrict__ Wq0, const T* __restrict__ Wq1,
    const T* __restrict__ Wd0, const T* __restrict__ Wd1, int n, float* __restrict__ ws)
{
    float xs[40];
#pragma unroll
    for (int q = 0; q < 5; ++q) ld8(x + n * 40 + q * 8, *(float(*)[8])(xs + q * 8));

    float q0[16];
#pragma unroll
    for (int w = 0; w < 16; ++w) q0[w] = 0.f;
#pragma unroll
    for (int u = 0; u < 16; ++u) {
        float r0[8], r1[8];
        ld8(Wq0 + u * 16, r0);
        ld8(Wq0 + u * 16 + 8, r1);
        const float xv = xs[u];
#pragma unroll
        for (int w = 0; w < 8; ++w) {
            q0[w]     = fmaf(r0[w], xv, q0[w]);
            q0[8 + w] = fmaf(r1[w], xv, q0[8 + w]);
        }
    }
#pragma unroll
    for (int w = 0; w < 16; ++w) q0[w] *= 0.25f;

    float p0[16];
#pragma unroll
    for (int v = 0; v < 16; ++v) p0[v] = 0.f;
#pragma unroll
    for (int w = 0; w < 16; ++w) {
        float r0[8], r1[8];
        ld8(Wd0 + w * 16, r0);
        ld8(Wd0 + w * 16 + 8, r1);
        const float qv = q0[w];
#pragma unroll
        for (int v = 0; v < 8; ++v) {
            p0[v]     = fmaf(r0[v], qv, p0[v]);
            p0[8 + v] = fmaf(r1[v], qv, p0[8 + v]);
        }
    }
    float* pn = ws + OFF_P + n * 40;
#pragma unroll
    for (int v = 0; v < 16; ++v) pn[v] = sanitize(p0[v] * INVS320);

    float q1[24];
#pragma unroll
    for (int k = 0; k < 24; ++k) q1[k] = 0.f;
#pragma unroll
    for (int u = 0; u < 8; ++u) {
        float r[8];
        ld8(Wq1 + u * 8, r);
        const float a0 = xs[16 + u * 3 + 0];
        const float a1 = xs[16 + u * 3 + 1];
        const float a2 = xs[16 + u * 3 + 2];
#pragma unroll
        for (int w = 0; w < 8; ++w) {
            q1[w * 3 + 0] = fmaf(r[w], a0, q1[w * 3 + 0]);
            q1[w * 3 + 1] = fmaf(r[w], a1, q1[w * 3 + 1]);
            q1[w * 3 + 2] = fmaf(r[w], a2, q1[w * 3 + 2]);
        }
    }
#pragma unroll
    for (int k = 0; k < 24; ++k) q1[k] *= INVS8;

    float p1[24];
#pragma unroll
    for (int k = 0; k < 24; ++k) p1[k] = 0.f;
#pragma unroll
    for (int w = 0; w < 8; ++w) {
        float r[8];
        ld8(Wd1 + w * 8, r);
        const float b0 = q1[w * 3 + 0];
        const float b1 = q1[w * 3 + 1];
        const float b2 = q1[w * 3 + 2];
#pragma unroll
        for (int v = 0; v < 8; ++v) {
            p1[v * 3 + 0] = fmaf(r[v], b0, p1[v * 3 + 0]);
            p1[v * 3 + 1] = fmaf(r[v], b1, p1[v * 3 + 1]);
            p1[v * 3 + 2] = fmaf(r[v], b2, p1[v * 3 + 2]);
        }
    }
    const float sc = INVS320 * INV_SQRT3;
#pragma unroll
    for (int k = 0; k < 24; ++k) pn[16 + k] = sanitize(p1[k] * sc);
}

// ---------------- gp (fused): [0,625) prep | [625,1875) G | [1875,1915) P ----------------
__global__ __launch_bounds__(256) void gp_kernel(
    const void* __restrict__ x,
    const void* __restrict__ Wq0, const void* __restrict__ Wq1,
    const void* __restrict__ Wk2, const void* __restrict__ Wv2,
    const void* __restrict__ Wd0, const void* __restrict__ Wd1,
    const void* __restrict__ ea, const void* __restrict__ amf,
    const void* __restrict__ Wk1, const void* __restrict__ Wv1,
    const int* __restrict__ ei,
    float* __restrict__ ws)
{
    const int f32 = *(const int*)ws;
    const int tid = threadIdx.x;
    const int blk = blockIdx.x;
    if (blk < 625) {
        do_prep(ea, amf, Wk1, Wv1, ei, ws, blk * 256 + tid, f32);
        return;
    }
    if (blk < 1875) {
        /* R24 decode: t -> (plane-pair j2, n, half u); adjacent lanes = channel pair */
        const int t  = (blk - 625) * 256 + tid;      /* < 320000 */
        const int j2 = t / 20000;                    /* 0..15 */
        const int r  = t - j2 * 20000;
        const int n  = r >> 1;
        const int u  = r & 1;
        const int p  = j2 >> 3;
        const int jj = j2 & 7;
        const int c  = jj * 2 + u;
        const void* W2b = p ? Wv2 : Wk2;
        if (f32) build_G((const float*)x, (const float*)W2b, n, p, c, u, ws);
        else     build_G((const __hip_bfloat16*)x, (const __hip_bfloat16*)W2b, n, p, c, u, ws);
        return;
    }
    {
        const int n = (blk - 1875) * 256 + tid;
        if (n >= N_CNT) return;
        if (f32) build_P((const float*)x, (const float*)Wq0, (const float*)Wq1,
                         (const float*)Wd0, (const float*)Wd1, n, ws);
        else     build_P((const __hip_bfloat16*)x, (const __hip_bfloat16*)Wq0,
                         (const __hip_bfloat16*)Wq1, (const __hip_bfloat16*)Wd0,
                         (const __hip_bfloat16*)Wd1, n, ws);
    }
}

// ---------------- dual scan (512 threads: half dst, half src) + zero Z at end ----------------
__global__ __launch_bounds__(512) void scan_kernel(float* __restrict__ ws)
{
    __shared__ int ssum[512];
    const int t    = threadIdx.x;
    const int half = t >> 8;
    const int lt   = t & 255;
    int* deg   = (int*)(ws + (half ? OFF_DEG2   : OFF_DEG));
    int* start = (int*)(ws + (half ? OFF_START2 : OFF_START));
    int* curs  = (int*)(ws + (half ? OFF_CURS2  : OFF_CURS));
    const int base = lt * 40;
    int s = 0;
    for (int k = 0; k < 40; ++k) {
        int idx = base + k;
        if (idx < N_CNT) s += deg[idx];
    }
    ssum[t] = s;
    __syncthreads();
    for (int off = 1; off < 256; off <<= 1) {
        int v = (lt >= off) ? ssum[t - off] : 0;
        __syncthreads();
        ssum[t] += v;
        __syncthreads();
    }
    int run = ssum[t] - s;
    for (int k = 0; k < 40; ++k) {
        int idx = base + k;
        if (idx < N_CNT) {
            start[idx] = run;
            curs[idx]  = run;
            run += deg[idx];
        }
    }
    if (lt == 255) start[N_CNT] = E_CNT;
    __syncthreads();                                   /* all deg reads done */
    for (int k = t; k < N_CNT; k += 512) ws[OFF_Z + k] = 0.f;   /* Z aliases DEG */
}

// ---------------- fill: src-CSR + dst-position per src-slot ----------------
__global__ __launch_bounds__(256) void fill_kernel(const int* __restrict__ ei, float* __restrict__ ws)
{
    const int e = blockIdx.x * 256 + threadIdx.x;      /* 625*256 = 160000 exact */
    int pd = atomicAdd((int*)(ws + OFF_CURS)  + ei[E_CNT + e], 1);
    int ps = atomicAdd((int*)(ws + OFF_CURS2) + ei[e], 1);
    ((int*)(ws + OFF_ELIST2))[ps] = e;
    ((int*)(ws + OFF_DPOS))[ps]   = pd;
}

// ---------------- edge-kernel helpers ----------------
/* contiguous half-row load: 12 uint4 = 48 packed u32 */
static __device__ __forceinline__ void load12c(unsigned (&ub)[48], const uint4* __restrict__ p0)
{
#pragma unroll
    for (int q = 0; q < 12; ++q) {
        uint4 v = p0[q];
        ub[4 * q + 0] = v.x; ub[4 * q + 1] = v.y;
        ub[4 * q + 2] = v.z; ub[4 * q + 3] = v.w;
    }
}

/* half0 (k 0..47): o0 += hs*G1 | t2a += hc*G2 | o1 += hs*G3, both channels fused via dot2.
   Coefficients split bf16-hi + bf16-residual (two chained dot2) -> >= old f32 accuracy. */
static __device__ __forceinline__ void accum_lo(const unsigned (&ub)[48],
    float h0, float h1, float sh0,
    float (&o0)[16], float (&o1)[24], float (&t2a)[8])
{
    unsigned hsH, hsL, hcH, hcL;
    splitpk(h0 * sh0, h1 * sh0, hsH, hsL);
    splitpk(h0, h1, hcH, hcL);
#pragma unroll
    for (int w = 0; w < 16; ++w)
        o0[w] = dot2bf(ub[w], hsL, dot2bf(ub[w], hsH, o0[w]));
#pragma unroll
    for (int w = 0; w < 8; ++w)
        t2a[w] = dot2bf(ub[16 + w], hcL, dot2bf(ub[16 + w], hcH, t2a[w]));
#pragma unroll
    for (int k = 0; k < 24; ++k)
        o1[k] = dot2bf(ub[24 + k], hsL, dot2bf(ub[24 + k], hsH, o1[k]));
}
/* half1 (k 48..95 = G4): o0[w] += h*(G4x*s1x + G4y*s1y + G4z*s1z), both channels fused */
static __device__ __forceinline__ void accum_hi(const unsigned (&ub)[48],
    float h0, float h1, float s1x, float s1y, float s1z, float (&o0)[16])
{
    unsigned hxH, hxL, hyH, hyL, hzH, hzL;
    splitpk(h0 * s1x, h1 * s1x, hxH, hxL);
    splitpk(h0 * s1y, h1 * s1y, hyH, hyL);
    splitpk(h0 * s1z, h1 * s1z, hzH, hzL);
#pragma unroll
    for (int w = 0; w < 16; ++w) {
        float acc = o0[w];
        acc = dot2bf(ub[3 * w + 0], hxL, dot2bf(ub[3 * w + 0], hxH, acc));
        acc = dot2bf(ub[3 * w + 1], hyL, dot2bf(ub[3 * w + 1], hyH, acc));
        acc = dot2bf(ub[3 * w + 2], hzL, dot2bf(ub[3 * w + 2], hzH, acc));
        o0[w] = acc;
    }
}

// ---------------- per-edge main kernel: dot2 accum over pair-interleaved rows ----------------
/* R24: same edge->lane mapping, same A/B double-buffer skeleton (48-u32 units), but
   accumulation via v_dot2_f32_bf16 on channel-pair-packed G rows: per round-pair
   192 dot2 + ~40 coeff ops vs 416 VALU before. Rows contiguous -> loads are
   base+imm-offset dwordx4. R15/R16/R19/R20/R21/R22 failure modes all avoided:
   no temp staging arrays, buffer sizes unchanged, one-edge-per-lane, no waves clause. */
__global__ __launch_bounds__(128) void edge_kernel(
    const int* __restrict__ ei, float* __restrict__ ws)
{
    const int tid  = threadIdx.x;
    const int pass = tid >> 6;          /* wave 0: K, wave 1: V */
    const int lane = tid & 63;
    /* XCD swizzle: give each XCD a contiguous src range (2496 = 8*312) */
    const int b  = blockIdx.x;
    const int lb = (b < 2496) ? ((b & 7) * 312 + (b >> 3)) : b;
    const int sidx = lb * 64 + lane;    /* src-sorted edge index; 2500*64 = 160000 exact */
    const int e    = ((const int*)(ws + OFF_ELIST2))[sidx];
    const int dpos = ((const int*)(ws + OFF_DPOS))[sidx];
    const int src  = ei[e];
    const int dst  = ei[E_CNT + e];

    /* row base for (pass, jj=0, src), uint4 units; jj stride = 240000 uint4 */
    const uint4* gb = (const uint4*)(ws + OFF_G) + ((size_t)pass * 80000 + src) * 24;
    unsigned A[48], B[48];
    load12c(A, gb);          /* (jj0, half0) */
    load12c(B, gb + 12);     /* (jj0, half1) */

    /* ---- sparse RBF: only bins i0=ceil(dsv)-2, i1=ceil(dsv)-1 can be nonzero ---- */
    const float d   = ws[OFF_AMFF + e];
    const float dsv = d * INV_STEP;
    const int i1 = (int)ceilf(dsv) - 1;
    const int i0 = i1 - 1;
    float e0 = 0.f, e1 = 0.f;
    {
        float t1 = dsv - (float)i0;                 /* >= 1 */
        float t2 = (float)(i0 + 2) - dsv;           /* in [0,1) */
        if (i0 >= 0 && i0 <= 15 && t2 > 0.f)
            e0 = EMB_C * expf(-1.f / t1 - 1.f / t2);
        float u1 = dsv - (float)i1;                 /* in (0,1] */
        float u2 = (float)(i1 + 2) - dsv;           /* >= 1 */
        if (i1 >= 0 && i1 <= 15 && u1 > 0.f)
            e1 = EMB_C * expf(-1.f / u1 - 1.f / u2);
    }
    const int r0i = (i0 < 0 ? 0 : (i0 > 15 ? 15 : i0)) << 4;
    const int r1i = (i1 < 0 ? 0 : (i1 > 15 ? 15 : i1)) << 4;

    const float* W1 = ws + (pass ? OFF_WV1F : OFF_WK1F);
    float h[16];
#pragma unroll
    for (int j = 0; j < 16; ++j) {
        float s = fmaf(e1, W1[r1i + j], e0 * W1[r0i + j]);
        s *= 0.25f;
        h[j] = s / (1.f + expf(-s));
    }

    const float4 eav = ((const float4*)(ws + OFF_EAF))[e];
    const float sh0 = eav.x, s1x = eav.y, s1y = eav.z, s1z = eav.w;

    float o0[16], o1[24], t2a[8];
#pragma unroll
    for (int i = 0; i < 16; ++i) o0[i] = 0.f;
#pragma unroll
    for (int i = 0; i < 24; ++i) o1[i] = 0.f;
#pragma unroll
    for (int i = 0; i < 8; ++i) t2a[i] = 0.f;

#pragma unroll
    for (int s = 0; s < 16; s += 2) {
        const int jj = s >> 1;
        accum_lo(A, h[2 * jj], h[2 * jj + 1], sh0, o0, o1, t2a);
        if (s + 2 < 16) load12c(A, gb + (size_t)(jj + 1) * 240000);
        accum_hi(B, h[2 * jj], h[2 * jj + 1], s1x, s1y, s1z, o0);
        if (s + 3 < 16) load12c(B, gb + (size_t)(jj + 1) * 240000 + 12);
    }

#pragma unroll
    for (int w = 0; w < 8; ++w) {
        o1[w * 3 + 0] = fmaf(t2a[w], s1x, o1[w * 3 + 0]);
        o1[w * 3 + 1] = fmaf(t2a[w], s1y, o1[w * 3 + 1]);
        o1[w * 3 + 2] = fmaf(t2a[w], s1z, o1[w * 3 + 2]);
    }

    if (pass == 0) {
        const float* pd = ws + OFF_P + dst * 40;
        float sc = 0.f;
#pragma unroll
        for (int j = 0; j < 16; ++j) sc = fmaf(o0[j], pd[j], sc);
#pragma unroll
        for (int j = 0; j < 24; ++j) sc = fmaf(o1[j], pd[16 + j], sc);
        sc = fminf(fmaxf(sc * KSCALE, -60.f), 60.f);
        float ct = 10.f * (1.f - d * 0.125f);
        float cutoff = (ct > 0.f) ? expf(-1.f / ct) : 0.f;
        float ev = fmaxf(cutoff * expf(sc), 0.f);
        ws[OFF_EXPV + dpos] = ev;                      /* dst-sorted slot */
        atomicAdd(ws + OFF_Z + dst, ev);
    } else {
        /* bf16 V store: 40 values -> 20 u32 -> 5 uint4 (once per thread) */
        float vo[40];
#pragma unroll
        for (int j = 0; j < 16; ++j) vo[j] = sanitize(o0[j] * KSCALE);
#pragma unroll
        for (int j = 0; j < 24; ++j) vo[16 + j] = sanitize(o1[j] * KSCALE);
        uint4 pk[5];
        unsigned* pu = (unsigned*)pk;
#pragma unroll
        for (int k = 0; k < 20; ++k)
            pu[k] = (unsigned)f2bf(vo[2 * k]) | ((unsigned)f2bf(vo[2 * k + 1]) << 16);
        uint4* vr = (uint4*)((unsigned short*)(ws + OFF_VBUF) + (size_t)dpos * 40);
#pragma unroll
        for (int q = 0; q < 5; ++q) vr[q] = pk[q];
    }
}

// ---------------- gather: one thread per (node, feature-quad); bf16 VBUF streaming ----------------
__global__ __launch_bounds__(256) void gather_kernel(
    const float* __restrict__ ws, void* __restrict__ out)
{
    const int i = blockIdx.x * 256 + threadIdx.x;
    if (i >= N_CNT * 10) return;
    const int n = i / 10;
    const int q = i - n * 10;
    const int* start = (const int*)(ws + OFF_START);
    const float* expv = ws + OFF_EXPV;
    const unsigned* Vb = (const unsigned*)(ws + OFF_VBUF);   /* bf16 pairs */
    const int s = start[n], t = start[n + 1];

    float zz = ws[OFF_Z + n];
    const float rz = (zz > 0.f) ? 1.f / zz : 1.f;

    float ax = 0.f, ay = 0.f, az = 0.f, aw = 0.f;
    for (int j = s; j < t; ++j) {
        const float we = sqrtf(fmaxf(expv[j] * rz, 0.f));
        uint2 u = *(const uint2*)(Vb + (size_t)j * 20 + 2 * q);   /* elements 4q..4q+3 */
        float2 v0 = bfp(u.x), v1 = bfp(u.y);
        ax = fmaf(we, v0.x, ax); ay = fmaf(we, v0.y, ay);
        az = fmaf(we, v1.x, az); aw = fmaf(we, v1.y, aw);
    }
    ax = sanitize(ax); ay = sanitize(ay); az = sanitize(az); aw = sanitize(aw);
    const int f32 = *(const int*)ws;
    if (f32) {
        float4 o; o.x = ax; o.y = ay; o.z = az; o.w = aw;
        ((float4*)out)[(size_t)n * 10 + q] = o;
    } else {
        uint2 o;
        o.x = (unsigned)f2bf(ax) | ((unsigned)f2bf(ay) << 16);
        o.y = (unsigned)f2bf(az) | ((unsigned)f2bf(aw) << 16);
        ((uint2*)out)[(size_t)n * 10 + q] = o;
    }
}

extern "C" void kernel_launch(void* const* d_in, const int* in_sizes, int n_in,
                              void* d_out, int out_size, void* d_ws, size_t ws_size,
                              hipStream_t stream)
{
    (void)in_sizes; (void)n_in; (void)out_size; (void)ws_size;
    const void* x   = d_in[0];
    const int*  ei  = (const int*)d_in[1];
    const void* ea  = d_in[2];
    const void* amf = d_in[5];
    const void* Wq0 = d_in[6];
    const void* Wq1 = d_in[7];
    const void* Wk1 = d_in[8];
    const void* Wk2 = d_in[9];
    const void* Wv1 = d_in[10];
    const void* Wv2 = d_in[11];
    const void* Wd0 = d_in[12];
    const void* Wd1 = d_in[13];

    float* ws = (float*)d_ws;

    init_kernel<<<79, 256, 0, stream>>>((const unsigned short*)x, ws);
    gp_kernel<<<1915, 256, 0, stream>>>(x, Wq0, Wq1, Wk2, Wv2, Wd0, Wd1,
                                        ea, amf, Wk1, Wv1, (const int*)ei, ws);
    scan_kernel<<<1, 512, 0, stream>>>(ws);
    fill_kernel<<<625, 256, 0, stream>>>(ei, ws);
    edge_kernel<<<2500, 128, 0, stream>>>(ei, ws);
    gather_kernel<<<(N_CNT * 10 + 255) / 256, 256, 0, stream>>>(ws, d_out);
}

// Round 10
// 291.775 us; speedup vs baseline: 1.0061x; 1.0061x over previous
//
#include <hip/hip_runtime.h>
#include <hip/hip_bf16.h>

#define E_CNT 160000
#define N_CNT 10000

#define INV_STEP   2.125f          /* 17/8 */
#define EMB_C      33.734292f      /* 1.14136 * e^2 * sqrt(16) */
#define INVS320    0.05590170f     /* 1/sqrt(320) */
#define INVS8      0.35355339f     /* 1/sqrt(8)   */
#define INV_SQRT3  0.57735027f
#define KSCALE     0.051031036f    /* 0.25 (w/sqrt16) * 1/sqrt(24) (fctp norm) */

/* ---- workspace layout (float-sized offsets) ---- */
#define OFF_FLAG   0          /* 16 floats reserved (int flag at [0]) */
#define OFF_EAF    400016     /* 640000 */
#define OFF_AMFF   1040016    /* 160000 */
#define OFF_WK1F   1200656    /* 256 */
#define OFF_WV1F   1200912    /* 256 */
#define OFF_P      1219600    /* 400000 */
#define OFF_EXPV   1619600    /* 160000 (dst-sorted order, fp32) */
#define OFF_VBUF   1779600    /* E*40 bf16 = 12.8 MB (dst-sorted order) */
#define OFF_DEG    8179600    /* 10000 ints (dst); reused as Z (zeroed at end of scan) */
#define OFF_Z      8179600    /* alias of OFF_DEG */
#define OFF_DEG2   8189600    /* 10000 ints (src) -- adjacent to DEG: single zero range */
#define OFF_START  8199600    /* 10001 ints */
#define OFF_START2 8209601    /* 10001 ints */
#define OFF_CURS   8219602    /* 10000 ints */
#define OFF_CURS2  8229602    /* 10000 ints */
#define OFF_DPOS   8239602    /* 160000 ints: dst-position of edge at src-sorted slot */
#define OFF_ELIST2 8399602    /* 160000 ints */
#define OFF_G      8559632    /* G: 16*24*10000 uint4 = 61.44 MB (same extent) */
/* total 23,919,632 floats = 95.7 MB (same extent as R5-R24 -- verified mapped) */

/* R25 G layout: channel-pair packed, n-FASTEST (the sacred property -- R19/R24 both
   proved fragmenting the per-wave n-contiguity costs 2x+). uint4 at
   ((p*8 + jj)*24 + kq)*10000 + n ; u32 j of it = (bf16 G_{2jj}[k], bf16 G_{2jj+1}[k]),
   k = 4*kq + j. k semantics = old out[] index: 0..15 G1(o0,hs) | 16..23 G2(t2a,hc) |
   24..47 G3(o1,hs) | 48..95 G4 (s1-dot, /sqrt3 baked). */

static __device__ __forceinline__ float bf2f(__hip_bfloat16 b) { return __bfloat162float(b); }
static __device__ __forceinline__ float sanitize(float v) {
    return fminf(fmaxf(v, -1e30f), 1e30f);
}
static __device__ __forceinline__ unsigned short f2bf(float f) {
    unsigned x = __float_as_uint(f);
    unsigned r = (x + 0x7fffu + ((x >> 16) & 1u)) >> 16;   /* RN-even */
    return (unsigned short)r;
}
static __device__ __forceinline__ float bflo(unsigned u) { return __uint_as_float(u << 16); }
static __device__ __forceinline__ float bfhi(unsigned u) { return __uint_as_float(u & 0xffff0000u); }
static __device__ __forceinline__ float2 bfp(unsigned u) {
    float2 r; r.x = bflo(u); r.y = bfhi(u); return r;
}

/* v_dot2_f32_bf16: d = a.lo*b.lo + a.hi*b.hi + c  (2 bf16 MACs, no unpack)
   [R24: verified assembles + passes absmax on gfx950] */
static __device__ __forceinline__ float dot2bf(unsigned a, unsigned b, float c)
{
    float d;
    asm("v_dot2_f32_bf16 %0, %1, %2, %3" : "=v"(d) : "v"(a), "v"(b), "v"(c));
    return d;
}
static __device__ __forceinline__ unsigned cvtpk2(float lo, float hi)
{
    unsigned r;
    asm("v_cvt_pk_bf16_f32 %0, %1, %2" : "=v"(r) : "v"(lo), "v"(hi));
    return r;
}
/* Dekker split: hi = bf16(a), lo = bf16(a - hi); applying both via chained dot2
   keeps the coefficient accurate to ~16 bits (>= old f32-coeff path; G's own
   bf16 noise dominates). [R24: absmax unchanged at 0.03125] */
static __device__ __forceinline__ void splitpk(float a0, float a1, unsigned& ph, unsigned& pl)
{
    ph = cvtpk2(a0, a1);
    pl = cvtpk2(a0 - bflo(ph), a1 - bfhi(ph));
}

/* load 4 consecutive floats from a maybe-bf16 / maybe-f32 buffer at element quad index i4 */
static __device__ __forceinline__ float4 load4(const void* p, int i4, int f32)
{
    if (f32) return ((const float4*)p)[i4];
    uint2 u = ((const uint2*)p)[i4];
    float4 r;
    r.x = bflo(u.x); r.y = bfhi(u.x);
    r.z = bflo(u.y); r.w = bfhi(u.y);
    return r;
}

/* 8-wide vector load: bf16 = one uint4 (16 B), f32 = two float4. p must be 16B-aligned. */
static __device__ __forceinline__ void ld8(const float* p, float (&r)[8])
{
    float4 a = ((const float4*)p)[0];
    float4 b = ((const float4*)p)[1];
    r[0] = a.x; r[1] = a.y; r[2] = a.z; r[3] = a.w;
    r[4] = b.x; r[5] = b.y; r[6] = b.z; r[7] = b.w;
}
static __device__ __forceinline__ void ld8(const __hip_bfloat16* p, float (&r)[8])
{
    uint4 u = *(const uint4*)p;
    r[0] = bflo(u.x); r[1] = bfhi(u.x); r[2] = bflo(u.y); r[3] = bfhi(u.y);
    r[4] = bflo(u.z); r[5] = bfhi(u.z); r[6] = bflo(u.w); r[7] = bfhi(u.w);
}

/* pair-exchange + pack 4 elements, store one uint4 at gs[kq*10000] on lane-parity
   `ustore`. Pack happens only inside the store branch (half the VALU). Keeps live
   range quad-granular (R24's pack-at-end pushed gp to 180 VGPR -- do not repeat). */
#define PSQ(gs, kq, a0, a1, a2, a3, u, ustore)                                 \
    do {                                                                       \
        float v0_ = __shfl_xor((a0), 1), v1_ = __shfl_xor((a1), 1);            \
        float v2_ = __shfl_xor((a2), 1), v3_ = __shfl_xor((a3), 1);            \
        if ((u) == (ustore)) {                                                 \
            float l0_ = (u) ? v0_ : (a0), h0_ = (u) ? (a0) : v0_;              \
            float l1_ = (u) ? v1_ : (a1), h1_ = (u) ? (a1) : v1_;              \
            float l2_ = (u) ? v2_ : (a2), h2_ = (u) ? (a2) : v2_;              \
            float l3_ = (u) ? v3_ : (a3), h3_ = (u) ? (a3) : v3_;              \
            uint4 t_;                                                          \
            t_.x = (unsigned)f2bf(l0_) | ((unsigned)f2bf(h0_) << 16);          \
            t_.y = (unsigned)f2bf(l1_) | ((unsigned)f2bf(h1_) << 16);          \
            t_.z = (unsigned)f2bf(l2_) | ((unsigned)f2bf(h2_) << 16);          \
            t_.w = (unsigned)f2bf(l3_) | ((unsigned)f2bf(h3_) << 16);          \
            (gs)[(size_t)(kq) * 10000] = t_;                                   \
        }                                                                      \
    } while (0)

// ---------------- init: zero DEG/DEG2 (20000 ints) + detect flag (block 0, wave 0) ----------------
__global__ __launch_bounds__(256) void init_kernel(
    const unsigned short* __restrict__ xb, float* __restrict__ ws)
{
    const int idx = blockIdx.x * 256 + threadIdx.x;    /* 79 blocks -> 20224 threads */
    if (idx < 20000) ((int*)(ws + OFF_DEG))[idx] = 0;
    if (blockIdx.x == 0 && threadIdx.x < 64) {
        const int lane = threadIdx.x;
        unsigned e0 = (unsigned)((xb[2 * lane] >> 7) & 0xFF);        /* even u16 = fp32 low halves */
        unsigned e1 = (unsigned)((xb[128 + 2 * lane] >> 7) & 0xFF);
        int c = (e0 >= 141 ? 1 : 0) + (e1 >= 141 ? 1 : 0);
#pragma unroll
        for (int off = 1; off < 64; off <<= 1) c += __shfl_xor(c, off);
        if (lane == 0) *(int*)ws = (c >= 8) ? 1 : 0;   /* 1 = inputs are fp32 */
    }
}

// ---------------- prep body: ingest EA/AMF/W1 + degree atomics ----------------
static __device__ __forceinline__ void do_prep(
    const void* __restrict__ ea, const void* __restrict__ amf,
    const void* __restrict__ Wk1, const void* __restrict__ Wv1,
    const int* __restrict__ ei, float* __restrict__ ws, int i, int f32)
{
    if (i < 160000) ((float4*)(ws + OFF_EAF))[i] = load4(ea, i, f32);
    if (i < 40000) {
        ((float4*)(ws + OFF_AMFF))[i] = load4(amf, i, f32);
#pragma unroll
        for (int k = 0; k < 4; ++k) {
            atomicAdd((int*)(ws + OFF_DEG)  + ei[E_CNT + 4 * i + k], 1);   /* dst degree */
            atomicAdd((int*)(ws + OFF_DEG2) + ei[4 * i + k], 1);           /* src degree */
        }
    }
    if (i < 64) {
        ((float4*)(ws + OFF_WK1F))[i] = load4(Wk1, i, f32);
        ((float4*)(ws + OFF_WV1F))[i] = load4(Wv1, i, f32);
    }
}

// ---------------- G builder: per-segment compute -> pair-pack -> n-fastest store ----------------
/* Lanes (2m, 2m+1) hold channels (2jj, 2jj+1) of the same n. After each segment
   completes, its values are exchanged, packed, and stored immediately (quad-granular),
   so the live set never exceeds seg-buffer + xs. Even lane stores kq 0..11, odd 12..23.
   G VALUES bit-identical to R23 (same f2bf); only arrangement changed. */
template <typename T>
static __device__ __forceinline__ void build_G(
    const T* __restrict__ x, const T* __restrict__ W2b, int n, int p, int c, int u,
    float* __restrict__ ws)
{
    float xs[40];
#pragma unroll
    for (int q = 0; q < 5; ++q) ld8(x + n * 40 + q * 8, *(float(*)[8])(xs + q * 8));
    const T* W2 = W2b + c * 576;
    uint4* gs = (uint4*)(ws + OFF_G) + (size_t)(p * 8 + (c >> 1)) * 240000 + n;

    /* seg1: k 0..15 -> kq 0..3 (even lane stores) */
    {
        float o[16];
#pragma unroll
        for (int k = 0; k < 16; ++k) o[k] = 0.f;
#pragma unroll
        for (int uu = 0; uu < 16; ++uu) {
            float r0[8], r1[8];
            ld8(W2 + uu * 16, r0);
            ld8(W2 + uu * 16 + 8, r1);
            const float xv = xs[uu];
#pragma unroll
            for (int w = 0; w < 8; ++w) {
                o[w]     = fmaf(r0[w], xv, o[w]);
                o[8 + w] = fmaf(r1[w], xv, o[8 + w]);
            }
        }
        PSQ(gs, 0, o[0],  o[1],  o[2],  o[3],  u, 0);
        PSQ(gs, 1, o[4],  o[5],  o[6],  o[7],  u, 0);
        PSQ(gs, 2, o[8],  o[9],  o[10], o[11], u, 0);
        PSQ(gs, 3, o[12], o[13], o[14], o[15], u, 0);
    }
    /* seg2: k 16..23 -> kq 4..5 */
    {
        float o[8];
#pragma unroll
        for (int k = 0; k < 8; ++k) o[k] = 0.f;
#pragma unroll
        for (int uu = 0; uu < 16; ++uu) {
            float r[8];
            ld8(W2 + 256 + uu * 8, r);
            const float xv = xs[uu];
#pragma unroll
            for (int w = 0; w < 8; ++w) o[w] = fmaf(r[w], xv, o[w]);
        }
        PSQ(gs, 4, o[0], o[1], o[2], o[3], u, 0);
        PSQ(gs, 5, o[4], o[5], o[6], o[7], u, 0);
    }
    /* seg3: k 24..47 -> kq 6..11 */
    {
        float o[24];
#pragma unroll
        for (int k = 0; k < 24; ++k) o[k] = 0.f;
#pragma unroll
        for (int uu = 0; uu < 8; ++uu) {
            float r[8];
            ld8(W2 + 384 + uu * 8, r);
            const float a0 = xs[16 + uu * 3 + 0];
            const float a1 = xs[16 + uu * 3 + 1];
            const float a2 = xs[16 + uu * 3 + 2];
#pragma unroll
            for (int w = 0; w < 8; ++w) {
                o[w * 3 + 0] = fmaf(r[w], a0, o[w * 3 + 0]);
                o[w * 3 + 1] = fmaf(r[w], a1, o[w * 3 + 1]);
                o[w * 3 + 2] = fmaf(r[w], a2, o[w * 3 + 2]);
            }
        }
        PSQ(gs, 6,  o[0],  o[1],  o[2],  o[3],  u, 0);
        PSQ(gs, 7,  o[4],  o[5],  o[6],  o[7],  u, 0);
        PSQ(gs, 8,  o[8],  o[9],  o[10], o[11], u, 0);
        PSQ(gs, 9,  o[12], o[13], o[14], o[15], u, 0);
        PSQ(gs, 10, o[16], o[17], o[18], o[19], u, 0);
        PSQ(gs, 11, o[20], o[21], o[22], o[23], u, 0);
    }
    /* seg4: k 48..95 -> kq 12..23 (odd lane stores), scaled by 1/sqrt3 */
    {
        float o[48];
#pragma unroll
        for (int k = 0; k < 48; ++k) o[k] = 0.f;
#pragma unroll
        for (int uu = 0; uu < 8; ++uu) {
            float r0[8], r1[8];
            ld8(W2 + 448 + uu * 16, r0);
            ld8(W2 + 448 + uu * 16 + 8, r1);
            const float a0 = xs[16 + uu * 3 + 0];
            const float a1 = xs[16 + uu * 3 + 1];
            const float a2 = xs[16 + uu * 3 + 2];
#pragma unroll
            for (int w = 0; w < 8; ++w) {
                o[w * 3 + 0] = fmaf(r0[w], a0, o[w * 3 + 0]);
                o[w * 3 + 1] = fmaf(r0[w], a1, o[w * 3 + 1]);
                o[w * 3 + 2] = fmaf(r0[w], a2, o[w * 3 + 2]);
                o[(8 + w) * 3 + 0] = fmaf(r1[w], a0, o[(8 + w) * 3 + 0]);
                o[(8 + w) * 3 + 1] = fmaf(r1[w], a1, o[(8 + w) * 3 + 1]);
                o[(8 + w) * 3 + 2] = fmaf(r1[w], a2, o[(8 + w) * 3 + 2]);
            }
        }
#pragma unroll
        for (int k = 0; k < 48; ++k) o[k] *= INV_SQRT3;
        PSQ(gs, 12, o[0],  o[1],  o[2],  o[3],  u, 1);
        PSQ(gs, 13, o[4],  o[5],  o[6],  o[7],  u, 1);
        PSQ(gs, 14, o[8],  o[9],  o[10], o[11], u, 1);
        PSQ(gs, 15, o[12], o[13], o[14], o[15], u, 1);
        PSQ(gs, 16, o[16], o[17], o[18], o[19], u, 1);
        PSQ(gs, 17, o[20], o[21], o[22], o[23], u, 1);
        PSQ(gs, 18, o[24], o[25], o[26], o[27], u, 1);
        PSQ(gs, 19, o[28], o[29], o[30], o[31], u, 1);
        PSQ(gs, 20, o[32], o[33], o[34], o[35], u, 1);
        PSQ(gs, 21, o[36], o[37], o[38], o[39], u, 1);
        PSQ(gs, 22, o[40], o[41], o[42], o[43], u, 1);
        PSQ(gs, 23, o[44], o[45], o[46], o[47], u, 1);
    }
}

// ---------------- P builder (vectorized loads) ----------------
template <typename T>
static __device__ __forceinline__ void build_P(
    const T* __restrict__ x, const T* __restrict__ Wq0, const T* __restrict__ Wq1,
    const T* __restrict__ Wd0, const T* __restrict__ Wd1, int n, float* __restrict__ ws)
{
    float xs[40];
#pragma unroll
    for (int q = 0; q < 5; ++q) ld8(x + n * 40 + q * 8, *(float(*)[8])(xs + q * 8));

    float q0[16];
#pragma unroll
    for (int w = 0; w < 16; ++w) q0[w] = 0.f;
#pragma unroll
    for (int u = 0; u < 16; ++u) {
        float r0[8], r1[8];
        ld8(Wq0 + u * 16, r0);
        ld8(Wq0 + u * 16 + 8, r1);
        const float xv = xs[u];
#pragma unroll
        for (int w = 0; w < 8; ++w) {
            q0[w]     = fmaf(r0[w], xv, q0[w]);
            q0[8 + w] = fmaf(r1[w], xv, q0[8 + w]);
        }
    }
#pragma unroll
    for (int w = 0; w < 16; ++w) q0[w] *= 0.25f;

    float p0[16];
#pragma unroll
    for (int v = 0; v < 16; ++v) p0[v] = 0.f;
#pragma unroll
    for (int w = 0; w < 16; ++w) {
        float r0[8], r1[8];
        ld8(Wd0 + w * 16, r0);
        ld8(Wd0 + w * 16 + 8, r1);
        const float qv = q0[w];
#pragma unroll
        for (int v = 0; v < 8; ++v) {
            p0[v]     = fmaf(r0[v], qv, p0[v]);
            p0[8 + v] = fmaf(r1[v], qv, p0[8 + v]);
        }
    }
    float* pn = ws + OFF_P + n * 40;
#pragma unroll
    for (int v = 0; v < 16; ++v) pn[v] = sanitize(p0[v] * INVS320);

    float q1[24];
#pragma unroll
    for (int k = 0; k < 24; ++k) q1[k] = 0.f;
#pragma unroll
    for (int u = 0; u < 8; ++u) {
        float r[8];
        ld8(Wq1 + u * 8, r);
        const float a0 = xs[16 + u * 3 + 0];
        const float a1 = xs[16 + u * 3 + 1];
        const float a2 = xs[16 + u * 3 + 2];
#pragma unroll
        for (int w = 0; w < 8; ++w) {
            q1[w * 3 + 0] = fmaf(r[w], a0, q1[w * 3 + 0]);
            q1[w * 3 + 1] = fmaf(r[w], a1, q1[w * 3 + 1]);
            q1[w * 3 + 2] = fmaf(r[w], a2, q1[w * 3 + 2]);
        }
    }
#pragma unroll
    for (int k = 0; k < 24; ++k) q1[k] *= INVS8;

    float p1[24];
#pragma unroll
    for (int k = 0; k < 24; ++k) p1[k] = 0.f;
#pragma unroll
    for (int w = 0; w < 8; ++w) {
        float r[8];
        ld8(Wd1 + w * 8, r);
        const float b0 = q1[w * 3 + 0];
        const float b1 = q1[w * 3 + 1];
        const float b2 = q1[w * 3 + 2];
#pragma unroll
        for (int v = 0; v < 8; ++v) {
            p1[v * 3 + 0] = fmaf(r[v], b0, p1[v * 3 + 0]);
            p1[v * 3 + 1] = fmaf(r[v], b1, p1[v * 3 + 1]);
            p1[v * 3 + 2] = fmaf(r[v], b2, p1[v * 3 + 2]);
        }
    }
    const float sc = INVS320 * INV_SQRT3;
#pragma unroll
    for (int k = 0; k < 24; ++k) pn[16 + k] = sanitize(p1[k] * sc);
}

// ---------------- gp (fused): [0,625) prep | [625,1875) G | [1875,1915) P ----------------
__global__ __launch_bounds__(256) void gp_kernel(
    const void* __restrict__ x,
    const void* __restrict__ Wq0, const void* __restrict__ Wq1,
    const void* __restrict__ Wk2, const void* __restrict__ Wv2,
    const void* __restrict__ Wd0, const void* __restrict__ Wd1,
    const void* __restrict__ ea, const void* __restrict__ amf,
    const void* __restrict__ Wk1, const void* __restrict__ Wv1,
    const int* __restrict__ ei,
    float* __restrict__ ws)
{
    const int f32 = *(const int*)ws;
    const int tid = threadIdx.x;
    const int blk = blockIdx.x;
    if (blk < 625) {
        do_prep(ea, amf, Wk1, Wv1, ei, ws, blk * 256 + tid, f32);
        return;
    }
    if (blk < 1875) {
        /* decode: adjacent lanes = channel pair of the same n (even lanes n-consecutive) */
        const int t  = (blk - 625) * 256 + tid;      /* < 320000 */
        const int j2 = t / 20000;                    /* 0..15 */
        const int r  = t - j2 * 20000;
        const int n  = r >> 1;
        const int u  = r & 1;
        const int p  = j2 >> 3;
        const int c  = (j2 & 7) * 2 + u;
        const void* W2b = p ? Wv2 : Wk2;
        if (f32) build_G((const float*)x, (const float*)W2b, n, p, c, u, ws);
        else     build_G((const __hip_bfloat16*)x, (const __hip_bfloat16*)W2b, n, p, c, u, ws);
        return;
    }
    {
        const int n = (blk - 1875) * 256 + tid;
        if (n >= N_CNT) return;
        if (f32) build_P((const float*)x, (const float*)Wq0, (const float*)Wq1,
                         (const float*)Wd0, (const float*)Wd1, n, ws);
        else     build_P((const __hip_bfloat16*)x, (const __hip_bfloat16*)Wq0,
                         (const __hip_bfloat16*)Wq1, (const __hip_bfloat16*)Wd0,
                         (const __hip_bfloat16*)Wd1, n, ws);
    }
}

// ---------------- dual scan (512 threads: half dst, half src) + zero Z at end ----------------
__global__ __launch_bounds__(512) void scan_kernel(float* __restrict__ ws)
{
    __shared__ int ssum[512];
    const int t    = threadIdx.x;
    const int half = t >> 8;
    const int lt   = t & 255;
    int* deg   = (int*)(ws + (half ? OFF_DEG2   : OFF_DEG));
    int* start = (int*)(ws + (half ? OFF_START2 : OFF_START));
    int* curs  = (int*)(ws + (half ? OFF_CURS2  : OFF_CURS));
    const int base = lt * 40;
    int s = 0;
    for (int k = 0; k < 40; ++k) {
        int idx = base + k;
        if (idx < N_CNT) s += deg[idx];
    }
    ssum[t] = s;
    __syncthreads();
    for (int off = 1; off < 256; off <<= 1) {
        int v = (lt >= off) ? ssum[t - off] : 0;
        __syncthreads();
        ssum[t] += v;
        __syncthreads();
    }
    int run = ssum[t] - s;
    for (int k = 0; k < 40; ++k) {
        int idx = base + k;
        if (idx < N_CNT) {
            start[idx] = run;
            curs[idx]  = run;
            run += deg[idx];
        }
    }
    if (lt == 255) start[N_CNT] = E_CNT;
    __syncthreads();                                   /* all deg reads done */
    for (int k = t; k < N_CNT; k += 512) ws[OFF_Z + k] = 0.f;   /* Z aliases DEG */
}

// ---------------- fill: src-CSR + dst-position per src-slot ----------------
__global__ __launch_bounds__(256) void fill_kernel(const int* __restrict__ ei, float* __restrict__ ws)
{
    const int e = blockIdx.x * 256 + threadIdx.x;      /* 625*256 = 160000 exact */
    int pd = atomicAdd((int*)(ws + OFF_CURS)  + ei[E_CNT + e], 1);
    int ps = atomicAdd((int*)(ws + OFF_CURS2) + ei[e], 1);
    ((int*)(ws + OFF_ELIST2))[ps] = e;
    ((int*)(ws + OFF_DPOS))[ps]   = pd;
}

// ---------------- edge-kernel helpers ----------------
/* plane-strided load: 12 uint4 at stride 10000 uint4 -- R23's proven shape
   (lanes 16B apart per instruction; ~4 lines per wave-load) */
static __device__ __forceinline__ void load48p(unsigned (&ub)[48], const uint4* __restrict__ p0)
{
#pragma unroll
    for (int q = 0; q < 12; ++q) {
        uint4 v = p0[(size_t)q * 10000];
        ub[4 * q + 0] = v.x; ub[4 * q + 1] = v.y;
        ub[4 * q + 2] = v.z; ub[4 * q + 3] = v.w;
    }
}

/* half0 (k 0..47): o0 += hs*G1 | t2a += hc*G2 | o1 += hs*G3, both channels via dot2.
   R15/R16/R19/R20/R21/R22/R24 failure modes avoided: no staging arrays, one edge
   per lane, n-fastest loads, buffer sizes unchanged, no waves-per-EU clause. */
static __device__ __forceinline__ void accum_lo(const unsigned (&ub)[48],
    float h0, float h1, float sh0,
    float (&o0)[16], float (&o1)[24], float (&t2a)[8])
{
    unsigned hsH, hsL, hcH, hcL;
    splitpk(h0 * sh0, h1 * sh0, hsH, hsL);
    splitpk(h0, h1, hcH, hcL);
#pragma unroll
    for (int w = 0; w < 16; ++w)
        o0[w] = dot2bf(ub[w], hsL, dot2bf(ub[w], hsH, o0[w]));
#pragma unroll
    for (int w = 0; w < 8; ++w)
        t2a[w] = dot2bf(ub[16 + w], hcL, dot2bf(ub[16 + w], hcH, t2a[w]));
#pragma unroll
    for (int k = 0; k < 24; ++k)
        o1[k] = dot2bf(ub[24 + k], hsL, dot2bf(ub[24 + k], hsH, o1[k]));
}
/* half1 (k 48..95 = G4): o0[w] += h*(G4x*s1x + G4y*s1y + G4z*s1z), both channels */
static __device__ __forceinline__ void accum_hi(const unsigned (&ub)[48],
    float h0, float h1, float s1x, float s1y, float s1z, float (&o0)[16])
{
    unsigned hxH, hxL, hyH, hyL, hzH, hzL;
    splitpk(h0 * s1x, h1 * s1x, hxH, hxL);
    splitpk(h0 * s1y, h1 * s1y, hyH, hyL);
    splitpk(h0 * s1z, h1 * s1z, hzH, hzL);
#pragma unroll
    for (int w = 0; w < 16; ++w) {
        float acc = o0[w];
        acc = dot2bf(ub[3 * w + 0], hxL, dot2bf(ub[3 * w + 0], hxH, acc));
        acc = dot2bf(ub[3 * w + 1], hyL, dot2bf(ub[3 * w + 1], hyH, acc));
        acc = dot2bf(ub[3 * w + 2], hzL, dot2bf(ub[3 * w + 2], hzH, acc));
        o0[w] = acc;
    }
}

// ---------------- per-edge main kernel: dot2 accum, R23 load shape ----------------
/* R25: R23's edge->lane mapping and plane-strided load48p double-buffer, with the
   R24-validated dot2 arithmetic on pair-packed planes. 8 jj rounds x (accum_lo A,
   prefetch A; accum_hi B, prefetch B). ~212 VALU/jj vs R23's ~420. */
__global__ __launch_bounds__(128) void edge_kernel(
    const int* __restrict__ ei, float* __restrict__ ws)
{
    const int tid  = threadIdx.x;
    const int pass = tid >> 6;          /* wave 0: K, wave 1: V */
    const int lane = tid & 63;
    /* XCD swizzle: give each XCD a contiguous src range (2496 = 8*312) */
    const int b  = blockIdx.x;
    const int lb = (b < 2496) ? ((b & 7) * 312 + (b >> 3)) : b;
    const int sidx = lb * 64 + lane;    /* src-sorted edge index; 2500*64 = 160000 exact */
    const int e    = ((const int*)(ws + OFF_ELIST2))[sidx];
    const int dpos = ((const int*)(ws + OFF_DPOS))[sidx];
    const int src  = ei[e];
    const int dst  = ei[E_CNT + e];

    /* base for (pass, jj=0, src); jj stride = 24 planes = 240000 uint4 */
    const uint4* gb = (const uint4*)(ws + OFF_G) + (size_t)pass * 1920000 + src;
    unsigned A[48], B[48];
    load48p(A, gb);            /* jj0 kq 0..11  (k 0..47)  */
    load48p(B, gb + 120000);   /* jj0 kq 12..23 (k 48..95) */

    /* ---- sparse RBF: only bins i0=ceil(dsv)-2, i1=ceil(dsv)-1 can be nonzero ---- */
    const float d   = ws[OFF_AMFF + e];
    const float dsv = d * INV_STEP;
    const int i1 = (int)ceilf(dsv) - 1;
    const int i0 = i1 - 1;
    float e0 = 0.f, e1 = 0.f;
    {
        float t1 = dsv - (float)i0;                 /* >= 1 */
        float t2 = (float)(i0 + 2) - dsv;           /* in [0,1) */
        if (i0 >= 0 && i0 <= 15 && t2 > 0.f)
            e0 = EMB_C * expf(-1.f / t1 - 1.f / t2);
        float u1 = dsv - (float)i1;                 /* in (0,1] */
        float u2 = (float)(i1 + 2) - dsv;           /* >= 1 */
        if (i1 >= 0 && i1 <= 15 && u1 > 0.f)
            e1 = EMB_C * expf(-1.f / u1 - 1.f / u2);
    }
    const int r0i = (i0 < 0 ? 0 : (i0 > 15 ? 15 : i0)) << 4;
    const int r1i = (i1 < 0 ? 0 : (i1 > 15 ? 15 : i1)) << 4;

    const float* W1 = ws + (pass ? OFF_WV1F : OFF_WK1F);
    float h[16];
#pragma unroll
    for (int j = 0; j < 16; ++j) {
        float s = fmaf(e1, W1[r1i + j], e0 * W1[r0i + j]);
        s *= 0.25f;
        h[j] = s / (1.f + expf(-s));
    }

    const float4 eav = ((const float4*)(ws + OFF_EAF))[e];
    const float sh0 = eav.x, s1x = eav.y, s1y = eav.z, s1z = eav.w;

    float o0[16], o1[24], t2a[8];
#pragma unroll
    for (int i = 0; i < 16; ++i) o0[i] = 0.f;
#pragma unroll
    for (int i = 0; i < 24; ++i) o1[i] = 0.f;
#pragma unroll
    for (int i = 0; i < 8; ++i) t2a[i] = 0.f;

#pragma unroll
    for (int jj = 0; jj < 8; ++jj) {
        accum_lo(A, h[2 * jj], h[2 * jj + 1], sh0, o0, o1, t2a);
        if (jj + 1 < 8) load48p(A, gb + (size_t)(jj + 1) * 240000);
        accum_hi(B, h[2 * jj], h[2 * jj + 1], s1x, s1y, s1z, o0);
        if (jj + 1 < 8) load48p(B, gb + (size_t)(jj + 1) * 240000 + 120000);
    }

#pragma unroll
    for (int w = 0; w < 8; ++w) {
        o1[w * 3 + 0] = fmaf(t2a[w], s1x, o1[w * 3 + 0]);
        o1[w * 3 + 1] = fmaf(t2a[w], s1y, o1[w * 3 + 1]);
        o1[w * 3 + 2] = fmaf(t2a[w], s1z, o1[w * 3 + 2]);
    }

    if (pass == 0) {
        const float* pd = ws + OFF_P + dst * 40;
        float sc = 0.f;
#pragma unroll
        for (int j = 0; j < 16; ++j) sc = fmaf(o0[j], pd[j], sc);
#pragma unroll
        for (int j = 0; j < 24; ++j) sc = fmaf(o1[j], pd[16 + j], sc);
        sc = fminf(fmaxf(sc * KSCALE, -60.f), 60.f);
        float ct = 10.f * (1.f - d * 0.125f);
        float cutoff = (ct > 0.f) ? expf(-1.f / ct) : 0.f;
        float ev = fmaxf(cutoff * expf(sc), 0.f);
        ws[OFF_EXPV + dpos] = ev;                      /* dst-sorted slot */
        atomicAdd(ws + OFF_Z + dst, ev);
    } else {
        /* bf16 V store: 40 values -> 20 u32 -> 5 uint4 (once per thread) */
        float vo[40];
#pragma unroll
        for (int j = 0; j < 16; ++j) vo[j] = sanitize(o0[j] * KSCALE);
#pragma unroll
        for (int j = 0; j < 24; ++j) vo[16 + j] = sanitize(o1[j] * KSCALE);
        uint4 pk[5];
        unsigned* pu = (unsigned*)pk;
#pragma unroll
        for (int k = 0; k < 20; ++k)
            pu[k] = (unsigned)f2bf(vo[2 * k]) | ((unsigned)f2bf(vo[2 * k + 1]) << 16);
        uint4* vr = (uint4*)((unsigned short*)(ws + OFF_VBUF) + (size_t)dpos * 40);
#pragma unroll
        for (int q = 0; q < 5; ++q) vr[q] = pk[q];
    }
}

// ---------------- gather: one thread per (node, feature-quad); bf16 VBUF streaming ----------------
__global__ __launch_bounds__(256) void gather_kernel(
    const float* __restrict__ ws, void* __restrict__ out)
{
    const int i = blockIdx.x * 256 + threadIdx.x;
    if (i >= N_CNT * 10) return;
    const int n = i / 10;
    const int q = i - n * 10;
    const int* start = (const int*)(ws + OFF_START);
    const float* expv = ws + OFF_EXPV;
    const unsigned* Vb = (const unsigned*)(ws + OFF_VBUF);   /* bf16 pairs */
    const int s = start[n], t = start[n + 1];

    float zz = ws[OFF_Z + n];
    const float rz = (zz > 0.f) ? 1.f / zz : 1.f;

    float ax = 0.f, ay = 0.f, az = 0.f, aw = 0.f;
    for (int j = s; j < t; ++j) {
        const float we = sqrtf(fmaxf(expv[j] * rz, 0.f));
        uint2 u = *(const uint2*)(Vb + (size_t)j * 20 + 2 * q);   /* elements 4q..4q+3 */
        float2 v0 = bfp(u.x), v1 = bfp(u.y);
        ax = fmaf(we, v0.x, ax); ay = fmaf(we, v0.y, ay);
        az = fmaf(we, v1.x, az); aw = fmaf(we, v1.y, aw);
    }
    ax = sanitize(ax); ay = sanitize(ay); az = sanitize(az); aw = sanitize(aw);
    const int f32 = *(const int*)ws;
    if (f32) {
        float4 o; o.x = ax; o.y = ay; o.z = az; o.w = aw;
        ((float4*)out)[(size_t)n * 10 + q] = o;
    } else {
        uint2 o;
        o.x = (unsigned)f2bf(ax) | ((unsigned)f2bf(ay) << 16);
        o.y = (unsigned)f2bf(az) | ((unsigned)f2bf(aw) << 16);
        ((uint2*)out)[(size_t)n * 10 + q] = o;
    }
}

extern "C" void kernel_launch(void* const* d_in, const int* in_sizes, int n_in,
                              void* d_out, int out_size, void* d_ws, size_t ws_size,
                              hipStream_t stream)
{
    (void)in_sizes; (void)n_in; (void)out_size; (void)ws_size;
    const void* x   = d_in[0];
    const int*  ei  = (const int*)d_in[1];
    const void* ea  = d_in[2];
    const void* amf = d_in[5];
    const void* Wq0 = d_in[6];
    const void* Wq1 = d_in[7];
    const void* Wk1 = d_in[8];
    const void* Wk2 = d_in[9];
    const void* Wv1 = d_in[10];
    const void* Wv2 = d_in[11];
    const void* Wd0 = d_in[12];
    const void* Wd1 = d_in[13];

    float* ws = (float*)d_ws;

    init_kernel<<<79, 256, 0, stream>>>((const unsigned short*)x, ws);
    gp_kernel<<<1915, 256, 0, stream>>>(x, Wq0, Wq1, Wk2, Wv2, Wd0, Wd1,
                                        ea, amf, Wk1, Wv1, (const int*)ei, ws);
    scan_kernel<<<1, 512, 0, stream>>>(ws);
    fill_kernel<<<625, 256, 0, stream>>>(ei, ws);
    edge_kernel<<<2500, 128, 0, stream>>>(ei, ws);
    gather_kernel<<<(N_CNT * 10 + 255) / 256, 256, 0, stream>>>(ws, d_out);
}

// Round 11
// 266.428 us; speedup vs baseline: 1.1018x; 1.0951x over previous
//
#include <hip/hip_runtime.h>
#include <hip/hip_bf16.h>

#define E_CNT 160000
#define N_CNT 10000

#define INV_STEP   2.125f          /* 17/8 */
#define EMB_C      33.734292f      /* 1.14136 * e^2 * sqrt(16) */
#define INVS320    0.05590170f     /* 1/sqrt(320) */
#define INVS8      0.35355339f     /* 1/sqrt(8)   */
#define INV_SQRT3  0.57735027f
#define KSCALE     0.051031036f    /* 0.25 (w/sqrt16) * 1/sqrt(24) (fctp norm) */

/* ---- workspace layout (float-sized offsets) ---- */
#define OFF_FLAG   0          /* 16 floats reserved (int flag at [0]) */
#define OFF_EAF    400016     /* 640000 */
#define OFF_AMFF   1040016    /* 160000 */
#define OFF_WK1F   1200656    /* 256 */
#define OFF_WV1F   1200912    /* 256 */
#define OFF_P      1219600    /* 400000 */
#define OFF_EXPV   1619600    /* 160000 (dst-sorted order, fp32) */
#define OFF_VBUF   1779600    /* E*40 bf16 = 12.8 MB (dst-sorted order) */
#define OFF_DEG    8179600    /* 10000 ints (dst); reused as Z (zeroed at end of scan) */
#define OFF_Z      8179600    /* alias of OFF_DEG */
#define OFF_DEG2   8189600    /* 10000 ints (src) -- adjacent to DEG: single zero range */
#define OFF_START  8199600    /* 10001 ints */
#define OFF_START2 8209601    /* 10001 ints */
#define OFF_CURS   8219602    /* 10000 ints */
#define OFF_CURS2  8229602    /* 10000 ints */
#define OFF_DPOS   8239602    /* 160000 ints: dst-position of edge at src-sorted slot */
#define OFF_ELIST2 8399602    /* 160000 ints */
#define OFF_G      8559632    /* G planes: 32*12*10000 uint4 = 61.44 MB */
/* total 23,919,632 floats = 95.7 MB (same extent as R5-R25 -- verified mapped) */

/* G plane layout: element (n, p, c, q) at uint4 index p*1920000 + c*120000 + q*10000 + n */

static __device__ __forceinline__ float bf2f(__hip_bfloat16 b) { return __bfloat162float(b); }
static __device__ __forceinline__ float sanitize(float v) {
    return fminf(fmaxf(v, -1e30f), 1e30f);
}
static __device__ __forceinline__ unsigned short f2bf(float f) {
    unsigned x = __float_as_uint(f);
    unsigned r = (x + 0x7fffu + ((x >> 16) & 1u)) >> 16;   /* RN-even */
    return (unsigned short)r;
}
static __device__ __forceinline__ float bflo(unsigned u) { return __uint_as_float(u << 16); }
static __device__ __forceinline__ float bfhi(unsigned u) { return __uint_as_float(u & 0xffff0000u); }
/* pair convert kept ONLY for gather (once per element there; R15 proved it hurts in edge's hot loop) */
static __device__ __forceinline__ float2 bfp(unsigned u) {
    float2 r; r.x = bflo(u); r.y = bfhi(u); return r;
}

/* load 4 consecutive floats from a maybe-bf16 / maybe-f32 buffer at element quad index i4 */
static __device__ __forceinline__ float4 load4(const void* p, int i4, int f32)
{
    if (f32) return ((const float4*)p)[i4];
    uint2 u = ((const uint2*)p)[i4];
    float4 r;
    r.x = bflo(u.x); r.y = bfhi(u.x);
    r.z = bflo(u.y); r.w = bfhi(u.y);
    return r;
}

/* 8-wide vector load: bf16 = one uint4 (16 B), f32 = two float4. p must be 16B-aligned. */
static __device__ __forceinline__ void ld8(const float* p, float (&r)[8])
{
    float4 a = ((const float4*)p)[0];
    float4 b = ((const float4*)p)[1];
    r[0] = a.x; r[1] = a.y; r[2] = a.z; r[3] = a.w;
    r[4] = b.x; r[5] = b.y; r[6] = b.z; r[7] = b.w;
}
static __device__ __forceinline__ void ld8(const __hip_bfloat16* p, float (&r)[8])
{
    uint4 u = *(const uint4*)p;
    r[0] = bflo(u.x); r[1] = bfhi(u.x); r[2] = bflo(u.y); r[3] = bfhi(u.y);
    r[4] = bflo(u.z); r[5] = bfhi(u.z); r[6] = bflo(u.w); r[7] = bfhi(u.w);
}

// ---------------- init: zero DEG/DEG2 (20000 ints) + detect flag (block 0, wave 0) ----------------
__global__ __launch_bounds__(256) void init_kernel(
    const unsigned short* __restrict__ xb, float* __restrict__ ws)
{
    const int idx = blockIdx.x * 256 + threadIdx.x;    /* 79 blocks -> 20224 threads */
    if (idx < 20000) ((int*)(ws + OFF_DEG))[idx] = 0;
    if (blockIdx.x == 0 && threadIdx.x < 64) {
        const int lane = threadIdx.x;
        unsigned e0 = (unsigned)((xb[2 * lane] >> 7) & 0xFF);        /* even u16 = fp32 low halves */
        unsigned e1 = (unsigned)((xb[128 + 2 * lane] >> 7) & 0xFF);
        int c = (e0 >= 141 ? 1 : 0) + (e1 >= 141 ? 1 : 0);
#pragma unroll
        for (int off = 1; off < 64; off <<= 1) c += __shfl_xor(c, off);
        if (lane == 0) *(int*)ws = (c >= 8) ? 1 : 0;   /* 1 = inputs are fp32 */
    }
}

// ---------------- prep body: ingest EA/AMF/W1 + degree atomics ----------------
static __device__ __forceinline__ void do_prep(
    const void* __restrict__ ea, const void* __restrict__ amf,
    const void* __restrict__ Wk1, const void* __restrict__ Wv1,
    const int* __restrict__ ei, float* __restrict__ ws, int i, int f32)
{
    if (i < 160000) ((float4*)(ws + OFF_EAF))[i] = load4(ea, i, f32);
    if (i < 40000) {
        ((float4*)(ws + OFF_AMFF))[i] = load4(amf, i, f32);
#pragma unroll
        for (int k = 0; k < 4; ++k) {
            atomicAdd((int*)(ws + OFF_DEG)  + ei[E_CNT + 4 * i + k], 1);   /* dst degree */
            atomicAdd((int*)(ws + OFF_DEG2) + ei[4 * i + k], 1);           /* src degree */
        }
    }
    if (i < 64) {
        ((float4*)(ws + OFF_WK1F))[i] = load4(Wk1, i, f32);
        ((float4*)(ws + OFF_WV1F))[i] = load4(Wv1, i, f32);
    }
}

// ---------------- G builder: vectorized loads, plane-transposed coalesced stores ----------------
template <typename T>
static __device__ __forceinline__ void build_G(
    const T* __restrict__ x, const T* __restrict__ W2b, int n, int p, int c, float* __restrict__ ws)
{
    float xs[40];
#pragma unroll
    for (int q = 0; q < 5; ++q) ld8(x + n * 40 + q * 8, *(float(*)[8])(xs + q * 8));
    const T* W2 = W2b + c * 576;

    float out[96];
#pragma unroll
    for (int k = 0; k < 96; ++k) out[k] = 0.f;

    /* seg1 */
#pragma unroll
    for (int u = 0; u < 16; ++u) {
        float r0[8], r1[8];
        ld8(W2 + u * 16, r0);
        ld8(W2 + u * 16 + 8, r1);
        const float xv = xs[u];
#pragma unroll
        for (int w = 0; w < 8; ++w) {
            out[w]     = fmaf(r0[w], xv, out[w]);
            out[8 + w] = fmaf(r1[w], xv, out[8 + w]);
        }
    }
    /* seg2 */
#pragma unroll
    for (int u = 0; u < 16; ++u) {
        float r[8];
        ld8(W2 + 256 + u * 8, r);
        const float xv = xs[u];
#pragma unroll
        for (int w = 0; w < 8; ++w) out[16 + w] = fmaf(r[w], xv, out[16 + w]);
    }
    /* seg3 */
#pragma unroll
    for (int u = 0; u < 8; ++u) {
        float r[8];
        ld8(W2 + 384 + u * 8, r);
        const float a0 = xs[16 + u * 3 + 0];
        const float a1 = xs[16 + u * 3 + 1];
        const float a2 = xs[16 + u * 3 + 2];
#pragma unroll
        for (int w = 0; w < 8; ++w) {
            out[24 + w * 3 + 0] = fmaf(r[w], a0, out[24 + w * 3 + 0]);
            out[24 + w * 3 + 1] = fmaf(r[w], a1, out[24 + w * 3 + 1]);
            out[24 + w * 3 + 2] = fmaf(r[w], a2, out[24 + w * 3 + 2]);
        }
    }
    /* seg4 (scaled by 1/sqrt3 below) */
#pragma unroll
    for (int u = 0; u < 8; ++u) {
        float r0[8], r1[8];
        ld8(W2 + 448 + u * 16, r0);
        ld8(W2 + 448 + u * 16 + 8, r1);
        const float a0 = xs[16 + u * 3 + 0];
        const float a1 = xs[16 + u * 3 + 1];
        const float a2 = xs[16 + u * 3 + 2];
#pragma unroll
        for (int w = 0; w < 8; ++w) {
            out[48 + w * 3 + 0] = fmaf(r0[w], a0, out[48 + w * 3 + 0]);
            out[48 + w * 3 + 1] = fmaf(r0[w], a1, out[48 + w * 3 + 1]);
            out[48 + w * 3 + 2] = fmaf(r0[w], a2, out[48 + w * 3 + 2]);
            out[48 + (8 + w) * 3 + 0] = fmaf(r1[w], a0, out[48 + (8 + w) * 3 + 0]);
            out[48 + (8 + w) * 3 + 1] = fmaf(r1[w], a1, out[48 + (8 + w) * 3 + 1]);
            out[48 + (8 + w) * 3 + 2] = fmaf(r1[w], a2, out[48 + (8 + w) * 3 + 2]);
        }
    }
#pragma unroll
    for (int k = 0; k < 48; ++k) out[48 + k] *= INV_SQRT3;

    uint4 ov[12];
    unsigned* ou = (unsigned*)ov;
#pragma unroll
    for (int k = 0; k < 48; ++k)
        ou[k] = (unsigned)f2bf(out[2 * k]) | ((unsigned)f2bf(out[2 * k + 1]) << 16);
    uint4* gb = (uint4*)(ws + OFF_G) + (size_t)(p * 16 + c) * 120000 + n;
#pragma unroll
    for (int q = 0; q < 12; ++q) gb[q * 10000] = ov[q];
}

// ---------------- P builder (vectorized loads) ----------------
template <typename T>
static __device__ __forceinline__ void build_P(
    const T* __restrict__ x, const T* __restrict__ Wq0, const T* __restrict__ Wq1,
    const T* __restrict__ Wd0, const T* __restrict__ Wd1, int n, float* __restrict__ ws)
{
    float xs[40];
#pragma unroll
    for (int q = 0; q < 5; ++q) ld8(x + n * 40 + q * 8, *(float(*)[8])(xs + q * 8));

    float q0[16];
#pragma unroll
    for (int w = 0; w < 16; ++w) q0[w] = 0.f;
#pragma unroll
    for (int u = 0; u < 16; ++u) {
        float r0[8], r1[8];
        ld8(Wq0 + u * 16, r0);
        ld8(Wq0 + u * 16 + 8, r1);
        const float xv = xs[u];
#pragma unroll
        for (int w = 0; w < 8; ++w) {
            q0[w]     = fmaf(r0[w], xv, q0[w]);
            q0[8 + w] = fmaf(r1[w], xv, q0[8 + w]);
        }
    }
#pragma unroll
    for (int w = 0; w < 16; ++w) q0[w] *= 0.25f;

    float p0[16];
#pragma unroll
    for (int v = 0; v < 16; ++v) p0[v] = 0.f;
#pragma unroll
    for (int w = 0; w < 16; ++w) {
        float r0[8], r1[8];
        ld8(Wd0 + w * 16, r0);
        ld8(Wd0 + w * 16 + 8, r1);
        const float qv = q0[w];
#pragma unroll
        for (int v = 0; v < 8; ++v) {
            p0[v]     = fmaf(r0[v], qv, p0[v]);
            p0[8 + v] = fmaf(r1[v], qv, p0[8 + v]);
        }
    }
    float* pn = ws + OFF_P + n * 40;
#pragma unroll
    for (int v = 0; v < 16; ++v) pn[v] = sanitize(p0[v] * INVS320);

    float q1[24];
#pragma unroll
    for (int k = 0; k < 24; ++k) q1[k] = 0.f;
#pragma unroll
    for (int u = 0; u < 8; ++u) {
        float r[8];
        ld8(Wq1 + u * 8, r);
        const float a0 = xs[16 + u * 3 + 0];
        const float a1 = xs[16 + u * 3 + 1];
        const float a2 = xs[16 + u * 3 + 2];
#pragma unroll
        for (int w = 0; w < 8; ++w) {
            q1[w * 3 + 0] = fmaf(r[w], a0, q1[w * 3 + 0]);
            q1[w * 3 + 1] = fmaf(r[w], a1, q1[w * 3 + 1]);
            q1[w * 3 + 2] = fmaf(r[w], a2, q1[w * 3 + 2]);
        }
    }
#pragma unroll
    for (int k = 0; k < 24; ++k) q1[k] *= INVS8;

    float p1[24];
#pragma unroll
    for (int k = 0; k < 24; ++k) p1[k] = 0.f;
#pragma unroll
    for (int w = 0; w < 8; ++w) {
        float r[8];
        ld8(Wd1 + w * 8, r);
        const float b0 = q1[w * 3 + 0];
        const float b1 = q1[w * 3 + 1];
        const float b2 = q1[w * 3 + 2];
#pragma unroll
        for (int v = 0; v < 8; ++v) {
            p1[v * 3 + 0] = fmaf(r[v], b0, p1[v * 3 + 0]);
            p1[v * 3 + 1] = fmaf(r[v], b1, p1[v * 3 + 1]);
            p1[v * 3 + 2] = fmaf(r[v], b2, p1[v * 3 + 2]);
        }
    }
    const float sc = INVS320 * INV_SQRT3;
#pragma unroll
    for (int k = 0; k < 24; ++k) pn[16 + k] = sanitize(p1[k] * sc);
}

// ---------------- gp (fused): [0,625) prep | [625,1875) G | [1875,1915) P ----------------
__global__ __launch_bounds__(256) void gp_kernel(
    const void* __restrict__ x,
    const void* __restrict__ Wq0, const void* __restrict__ Wq1,
    const void* __restrict__ Wk2, const void* __restrict__ Wv2,
    const void* __restrict__ Wd0, const void* __restrict__ Wd1,
    const void* __restrict__ ea, const void* __restrict__ amf,
    const void* __restrict__ Wk1, const void* __restrict__ Wv1,
    const int* __restrict__ ei,
    float* __restrict__ ws)
{
    const int f32 = *(const int*)ws;
    const int tid = threadIdx.x;
    const int blk = blockIdx.x;
    if (blk < 625) {
        do_prep(ea, amf, Wk1, Wv1, ei, ws, blk * 256 + tid, f32);
        return;
    }
    if (blk < 1875) {
        const int t = (blk - 625) * 256 + tid;       /* < 320000 */
        const int p   = t / 160000;
        const int rem = t - p * 160000;
        const int c   = rem / 10000;
        const int n   = rem - c * 10000;
        const void* W2b = p ? Wv2 : Wk2;
        if (f32) build_G((const float*)x, (const float*)W2b, n, p, c, ws);
        else     build_G((const __hip_bfloat16*)x, (const __hip_bfloat16*)W2b, n, p, c, ws);
        return;
    }
    {
        const int n = (blk - 1875) * 256 + tid;
        if (n >= N_CNT) return;
        if (f32) build_P((const float*)x, (const float*)Wq0, (const float*)Wq1,
                         (const float*)Wd0, (const float*)Wd1, n, ws);
        else     build_P((const __hip_bfloat16*)x, (const __hip_bfloat16*)Wq0,
                         (const __hip_bfloat16*)Wq1, (const __hip_bfloat16*)Wd0,
                         (const __hip_bfloat16*)Wd1, n, ws);
    }
}

// ---------------- dual scan (512 threads: half dst, half src) + zero Z at end ----------------
__global__ __launch_bounds__(512) void scan_kernel(float* __restrict__ ws)
{
    __shared__ int ssum[512];
    const int t    = threadIdx.x;
    const int half = t >> 8;
    const int lt   = t & 255;
    int* deg   = (int*)(ws + (half ? OFF_DEG2   : OFF_DEG));
    int* start = (int*)(ws + (half ? OFF_START2 : OFF_START));
    int* curs  = (int*)(ws + (half ? OFF_CURS2  : OFF_CURS));
    const int base = lt * 40;
    int s = 0;
    for (int k = 0; k < 40; ++k) {
        int idx = base + k;
        if (idx < N_CNT) s += deg[idx];
    }
    ssum[t] = s;
    __syncthreads();
    for (int off = 1; off < 256; off <<= 1) {
        int v = (lt >= off) ? ssum[t - off] : 0;
        __syncthreads();
        ssum[t] += v;
        __syncthreads();
    }
    int run = ssum[t] - s;
    for (int k = 0; k < 40; ++k) {
        int idx = base + k;
        if (idx < N_CNT) {
            start[idx] = run;
            curs[idx]  = run;
            run += deg[idx];
        }
    }
    if (lt == 255) start[N_CNT] = E_CNT;
    __syncthreads();                                   /* all deg reads done */
    for (int k = t; k < N_CNT; k += 512) ws[OFF_Z + k] = 0.f;   /* Z aliases DEG */
}

// ---------------- fill: src-CSR + dst-position per src-slot ----------------
__global__ __launch_bounds__(256) void fill_kernel(const int* __restrict__ ei, float* __restrict__ ws)
{
    const int e = blockIdx.x * 256 + threadIdx.x;      /* 625*256 = 160000 exact */
    int pd = atomicAdd((int*)(ws + OFF_CURS)  + ei[E_CNT + e], 1);
    int ps = atomicAdd((int*)(ws + OFF_CURS2) + ei[e], 1);
    ((int*)(ws + OFF_ELIST2))[ps] = e;
    ((int*)(ws + OFF_DPOS))[ps]   = pd;
}

// ---------------- edge-kernel helpers ----------------
/* plane-strided load: 12 uint4 at stride 10000 uint4 (160 KB) */
static __device__ __forceinline__ void load48p(unsigned (&ub)[48], const uint4* __restrict__ p0)
{
#pragma unroll
    for (int q = 0; q < 12; ++q) {
        uint4 v = p0[(size_t)q * 10000];
        ub[4 * q + 0] = v.x; ub[4 * q + 1] = v.y;
        ub[4 * q + 2] = v.z; ub[4 * q + 3] = v.w;
    }
}

/* R14-proven bit-twiddle accumulate: strict FIFO consumption, no temp arrays.
   Failure-mode ledger (do not reintroduce):
   R15: pair-cvt staging here ~40us. R16: rolling 3-buffer chunk -> scratch spill.
   R19: channel-split across lanes -> load fragmentation (135us). R20: K/V block
   split -> metadata dup (64us). R21/R22: min-waves>=4 -> VGPR crush + spill.
   R24/R25: dot2+pair-packed G -> gp register/latency regression (total +27us). */
static __device__ __forceinline__ void accum48(const unsigned (&ub)[48], float hc, float sh0,
    float s1x, float s1y, float s1z,
    float (&o0)[16], float (&o1)[24], float (&t2a)[8])
{
    const float hs = hc * sh0;
#define GVAL(k) (((k) & 1) ? bfhi(ub[(k) >> 1]) : bflo(ub[(k) >> 1]))
#pragma unroll
    for (int w = 0; w < 16; ++w) o0[w] = fmaf(hs, GVAL(w), o0[w]);
#pragma unroll
    for (int w = 0; w < 8; ++w) t2a[w] = fmaf(hc, GVAL(16 + w), t2a[w]);
#pragma unroll
    for (int k = 0; k < 24; ++k) o1[k] = fmaf(hs, GVAL(24 + k), o1[k]);
#pragma unroll
    for (int w = 0; w < 16; ++w) {
        float g = GVAL(48 + w * 3 + 0) * s1x;
        g = fmaf(GVAL(48 + w * 3 + 1), s1y, g);
        g = fmaf(GVAL(48 + w * 3 + 2), s1z, g);
        o0[w] = fmaf(hc, g, o0[w]);
    }
#undef GVAL
}

// ---------------- per-edge main kernel: R23 exact (best verified: 59.0us edge, 265us total) ----------------
__global__ __launch_bounds__(128) void edge_kernel(
    const int* __restrict__ ei, float* __restrict__ ws)
{
    const int tid  = threadIdx.x;
    const int pass = tid >> 6;          /* wave 0: K, wave 1: V */
    const int lane = tid & 63;
    /* XCD swizzle: give each XCD a contiguous src range (2496 = 8*312) */
    const int b  = blockIdx.x;
    const int lb = (b < 2496) ? ((b & 7) * 312 + (b >> 3)) : b;
    const int sidx = lb * 64 + lane;    /* src-sorted edge index; 2500*64 = 160000 exact */
    const int e    = ((const int*)(ws + OFF_ELIST2))[sidx];
    const int dpos = ((const int*)(ws + OFF_DPOS))[sidx];
    const int src  = ei[e];
    const int dst  = ei[E_CNT + e];

    /* plane-layout base for this (src, pass) */
    const uint4* gb = (const uint4*)(ws + OFF_G) + (size_t)pass * 1920000 + src;
    unsigned A[48], B[48];
    load48p(A, gb);
    load48p(B, gb + 120000);

    /* ---- sparse RBF: only bins i0=ceil(dsv)-2, i1=ceil(dsv)-1 can be nonzero ---- */
    const float d   = ws[OFF_AMFF + e];
    const float dsv = d * INV_STEP;
    const int i1 = (int)ceilf(dsv) - 1;
    const int i0 = i1 - 1;
    float e0 = 0.f, e1 = 0.f;
    {
        float t1 = dsv - (float)i0;                 /* >= 1 */
        float t2 = (float)(i0 + 2) - dsv;           /* in [0,1) */
        if (i0 >= 0 && i0 <= 15 && t2 > 0.f)
            e0 = EMB_C * expf(-1.f / t1 - 1.f / t2);
        float u1 = dsv - (float)i1;                 /* in (0,1] */
        float u2 = (float)(i1 + 2) - dsv;           /* >= 1 */
        if (i1 >= 0 && i1 <= 15 && u1 > 0.f)
            e1 = EMB_C * expf(-1.f / u1 - 1.f / u2);
    }
    const int r0i = (i0 < 0 ? 0 : (i0 > 15 ? 15 : i0)) << 4;
    const int r1i = (i1 < 0 ? 0 : (i1 > 15 ? 15 : i1)) << 4;

    const float* W1 = ws + (pass ? OFF_WV1F : OFF_WK1F);
    float h[16];
#pragma unroll
    for (int j = 0; j < 16; ++j) {
        float s = fmaf(e1, W1[r1i + j], e0 * W1[r0i + j]);
        s *= 0.25f;
        h[j] = s / (1.f + expf(-s));
    }

    const float4 eav = ((const float4*)(ws + OFF_EAF))[e];
    const float sh0 = eav.x, s1x = eav.y, s1y = eav.z, s1z = eav.w;

    float o0[16], o1[24], t2a[8];
#pragma unroll
    for (int i = 0; i < 16; ++i) o0[i] = 0.f;
#pragma unroll
    for (int i = 0; i < 24; ++i) o1[i] = 0.f;
#pragma unroll
    for (int i = 0; i < 8; ++i) t2a[i] = 0.f;

#pragma unroll
    for (int c = 0; c < 16; c += 2) {
        accum48(A, h[c], sh0, s1x, s1y, s1z, o0, o1, t2a);
        if (c + 2 < 16) load48p(A, gb + (size_t)(c + 2) * 120000);
        accum48(B, h[c + 1], sh0, s1x, s1y, s1z, o0, o1, t2a);
        if (c + 3 < 16) load48p(B, gb + (size_t)(c + 3) * 120000);
    }

#pragma unroll
    for (int w = 0; w < 8; ++w) {
        o1[w * 3 + 0] = fmaf(t2a[w], s1x, o1[w * 3 + 0]);
        o1[w * 3 + 1] = fmaf(t2a[w], s1y, o1[w * 3 + 1]);
        o1[w * 3 + 2] = fmaf(t2a[w], s1z, o1[w * 3 + 2]);
    }

    if (pass == 0) {
        const float* pd = ws + OFF_P + dst * 40;
        float sc = 0.f;
#pragma unroll
        for (int j = 0; j < 16; ++j) sc = fmaf(o0[j], pd[j], sc);
#pragma unroll
        for (int j = 0; j < 24; ++j) sc = fmaf(o1[j], pd[16 + j], sc);
        sc = fminf(fmaxf(sc * KSCALE, -60.f), 60.f);
        float ct = 10.f * (1.f - d * 0.125f);
        float cutoff = (ct > 0.f) ? expf(-1.f / ct) : 0.f;
        float ev = fmaxf(cutoff * expf(sc), 0.f);
        ws[OFF_EXPV + dpos] = ev;                      /* dst-sorted slot */
        atomicAdd(ws + OFF_Z + dst, ev);
    } else {
        /* bf16 V store: 40 values -> 20 u32 -> 5 uint4 (once per thread) */
        float vo[40];
#pragma unroll
        for (int j = 0; j < 16; ++j) vo[j] = sanitize(o0[j] * KSCALE);
#pragma unroll
        for (int j = 0; j < 24; ++j) vo[16 + j] = sanitize(o1[j] * KSCALE);
        uint4 pk[5];
        unsigned* pu = (unsigned*)pk;
#pragma unroll
        for (int k = 0; k < 20; ++k)
            pu[k] = (unsigned)f2bf(vo[2 * k]) | ((unsigned)f2bf(vo[2 * k + 1]) << 16);
        uint4* vr = (uint4*)((unsigned short*)(ws + OFF_VBUF) + (size_t)dpos * 40);
#pragma unroll
        for (int q = 0; q < 5; ++q) vr[q] = pk[q];
    }
}

// ---------------- gather: one thread per (node, feature-quad); bf16 VBUF streaming ----------------
__global__ __launch_bounds__(256) void gather_kernel(
    const float* __restrict__ ws, void* __restrict__ out)
{
    const int i = blockIdx.x * 256 + threadIdx.x;
    if (i >= N_CNT * 10) return;
    const int n = i / 10;
    const int q = i - n * 10;
    const int* start = (const int*)(ws + OFF_START);
    const float* expv = ws + OFF_EXPV;
    const unsigned* Vb = (const unsigned*)(ws + OFF_VBUF);   /* bf16 pairs */
    const int s = start[n], t = start[n + 1];

    float zz = ws[OFF_Z + n];
    const float rz = (zz > 0.f) ? 1.f / zz : 1.f;

    float ax = 0.f, ay = 0.f, az = 0.f, aw = 0.f;
    for (int j = s; j < t; ++j) {
        const float we = sqrtf(fmaxf(expv[j] * rz, 0.f));
        uint2 u = *(const uint2*)(Vb + (size_t)j * 20 + 2 * q);   /* elements 4q..4q+3 */
        float2 v0 = bfp(u.x), v1 = bfp(u.y);
        ax = fmaf(we, v0.x, ax); ay = fmaf(we, v0.y, ay);
        az = fmaf(we, v1.x, az); aw = fmaf(we, v1.y, aw);
    }
    ax = sanitize(ax); ay = sanitize(ay); az = sanitize(az); aw = sanitize(aw);
    const int f32 = *(const int*)ws;
    if (f32) {
        float4 o; o.x = ax; o.y = ay; o.z = az; o.w = aw;
        ((float4*)out)[(size_t)n * 10 + q] = o;
    } else {
        uint2 o;
        o.x = (unsigned)f2bf(ax) | ((unsigned)f2bf(ay) << 16);
        o.y = (unsigned)f2bf(az) | ((unsigned)f2bf(aw) << 16);
        ((uint2*)out)[(size_t)n * 10 + q] = o;
    }
}

extern "C" void kernel_launch(void* const* d_in, const int* in_sizes, int n_in,
                              void* d_out, int out_size, void* d_ws, size_t ws_size,
                              hipStream_t stream)
{
    (void)in_sizes; (void)n_in; (void)out_size; (void)ws_size;
    const void* x   = d_in[0];
    const int*  ei  = (const int*)d_in[1];
    const void* ea  = d_in[2];
    const void* amf = d_in[5];
    const void* Wq0 = d_in[6];
    const void* Wq1 = d_in[7];
    const void* Wk1 = d_in[8];
    const void* Wk2 = d_in[9];
    const void* Wv1 = d_in[10];
    const void* Wv2 = d_in[11];
    const void* Wd0 = d_in[12];
    const void* Wd1 = d_in[13];

    float* ws = (float*)d_ws;

    init_kernel<<<79, 256, 0, stream>>>((const unsigned short*)x, ws);
    gp_kernel<<<1915, 256, 0, stream>>>(x, Wq0, Wq1, Wk2, Wv2, Wd0, Wd1,
                                        ea, amf, Wk1, Wv1, (const int*)ei, ws);
    scan_kernel<<<1, 512, 0, stream>>>(ws);
    fill_kernel<<<625, 256, 0, stream>>>(ei, ws);
    edge_kernel<<<2500, 128, 0, stream>>>(ei, ws);
    gather_kernel<<<(N_CNT * 10 + 255) / 256, 256, 0, stream>>>(ws, d_out);
}